// Round 5
// baseline (51.402 us; speedup 1.0000x reference)
//
#include <hip/hip_runtime.h>
#include <math.h>

namespace {

constexpr int IMG  = 128;
constexpr int NPIX = IMG * IMG;
constexpr int B    = 4;
constexpr int V    = 600;
constexpr int F    = 1000;
constexpr int SEG  = 32;            // faces per passB block (fixed work quantum)
constexpr int NSEG = 32;            // 32*32 = 1024 >= F worst case
constexpr float FOCALF = 1.5f;
constexpr float EPSF   = 1e-8f;
constexpr float SLACK  = 1e-5f;     // >> max rounding error of w (~3e-6)

__device__ inline float seg_dist2(float px, float py, float ax, float ay,
                                  float bx, float by) {
#pragma clang fp contract(off)
    float ex = bx - ax, ey = by - ay;
    float dx = px - ax, dy = py - ay;
    float ee = fmaxf(ex * ex + ey * ey, EPSF);
    float t  = (dx * ex + dy * ey) / ee;
    t = fminf(fmaxf(t, 0.0f), 1.0f);
    float rx = dx - t * ex;
    float ry = dy - t * ey;
    return rx * rx + ry * ry;
}

// facedata layout [b][f][16]:
//  0:e0x 1:e0y 2:bx 3:by | 4:e1x 5:e1y 6:cx 7:cy | 8:e2x 9:e2y 10:ax 11:ay |
// 12:den 13:az 14:bz 15:cz      (den==0 marks degenerate/culled)
// Also clears zbest (one u64 per pixel) — fused to save a launch.
__global__ __launch_bounds__(256) void setup_clear(const float* __restrict__ verts,
                                                   const int* __restrict__ faces,
                                                   float* __restrict__ fdata,
                                                   unsigned long long* __restrict__ zbest) {
#pragma clang fp contract(off)
    int t = blockIdx.x * 256 + threadIdx.x;   // grid covers B*NPIX = 65536
    zbest[t] = ~0ULL;
    if (t >= B * F) return;
    int b = t / F, f = t - b * F;
    int i0 = faces[f * 3 + 0], i1 = faces[f * 3 + 1], i2 = faces[f * 3 + 2];
    const float* vb = verts + (size_t)b * V * 3;
    float x0 = vb[i0 * 3], y0 = vb[i0 * 3 + 1], z0 = vb[i0 * 3 + 2];
    float x1 = vb[i1 * 3], y1 = vb[i1 * 3 + 1], z1 = vb[i1 * 3 + 2];
    float x2 = vb[i2 * 3], y2 = vb[i2 * 3 + 1], z2 = vb[i2 * 3 + 2];
    // exact reference projection
    float ax = (FOCALF * x0) / z0, ay = (FOCALF * y0) / z0;
    float bx = (FOCALF * x1) / z1, by = (FOCALF * y1) / z1;
    float cx = (FOCALF * x2) / z2, cy = (FOCALF * y2) / z2;
    // edge vectors (identical rounding to reference's inline subtractions)
    float e0x = cx - bx, e0y = cy - by;   // edge for w0 (v1->v2), base b
    float e1x = ax - cx, e1y = ay - cy;   // edge for w1 (v2->v0), base c
    float e2x = bx - ax, e2y = by - ay;   // edge for w2 (v0->v1), base a
    float den = e2x * (cy - ay) - e2y * (cx - ax);   // == reference area tree
    if (!(fabsf(den) > EPSF)) den = 0.0f;
    float* o = fdata + ((size_t)t << 4);
    o[0]  = e0x; o[1]  = e0y; o[2]  = bx;  o[3]  = by;
    o[4]  = e1x; o[5]  = e1y; o[6]  = cx;  o[7]  = cy;
    o[8]  = e2x; o[9]  = e2y; o[10] = ax;  o[11] = ay;
    o[12] = den; o[13] = z0;  o[14] = z1;  o[15] = z2;
}

// binA: one block per (image, 16x16 tile). All 256 threads test all F faces
// (4 each) with the conservative half-plane test; survivors are compacted
// into a per-tile global u16 list (order arbitrary — merge is order-free).
__global__ __launch_bounds__(256) void binA(const float* __restrict__ fdata,
                                            unsigned short* __restrict__ slist,
                                            int* __restrict__ scount) {
#pragma clang fp contract(off)
    __shared__ int scnt;
    const int tid  = threadIdx.x;
    const int bt   = blockIdx.x;          // b*64 + tile
    const int b    = bt >> 6;
    const int tile = bt & 63;
    if (tid == 0) scnt = 0;
    __syncthreads();

    const int ix0 = (tile & 7) * 16, iy0 = (tile >> 3) * 16;
    const float pxmax = 1.0f - (2.0f * (float)ix0 + 1.0f) / (float)IMG;
    const float pxmin = 1.0f - (2.0f * (float)(ix0 + 15) + 1.0f) / (float)IMG;
    const float pymax = 1.0f - (2.0f * (float)iy0 + 1.0f) / (float)IMG;
    const float pymin = 1.0f - (2.0f * (float)(iy0 + 15) + 1.0f) / (float)IMG;

    for (int f = tid; f < F; f += 256) {
        const float4* fd4 = (const float4*)(fdata + (((size_t)b * F + f) << 4));
        float4 q0 = fd4[0], q1 = fd4[1], q2 = fd4[2], q3 = fd4[3];
        float den = q3.x;
        if (den != 0.0f) {
            float s = den > 0.0f ? 1.0f : -1.0f;
            bool pass = true;
            {
                float gx = s * q0.x, gy = s * q0.y;
                float pyc = gx >= 0.0f ? pymax : pymin;
                float pxc = gy >= 0.0f ? pxmin : pxmax;
                pass &= (gx * (pyc - q0.w) - gy * (pxc - q0.z)) >= -SLACK;
            }
            {
                float gx = s * q1.x, gy = s * q1.y;
                float pyc = gx >= 0.0f ? pymax : pymin;
                float pxc = gy >= 0.0f ? pxmin : pxmax;
                pass &= (gx * (pyc - q1.w) - gy * (pxc - q1.z)) >= -SLACK;
            }
            {
                float gx = s * q2.x, gy = s * q2.y;
                float pyc = gx >= 0.0f ? pymax : pymin;
                float pxc = gy >= 0.0f ? pxmin : pxmax;
                pass &= (gx * (pyc - q2.w) - gy * (pxc - q2.z)) >= -SLACK;
            }
            if (pass) {
                int slot = atomicAdd(&scnt, 1);
                slist[(size_t)bt * F + slot] = (unsigned short)f;
            }
        }
    }
    __syncthreads();
    if (tid == 0) scount[bt] = scnt;
}

// passB: grid (B*64 tiles, NSEG segments). Each live block: exactly SEG (or
// remainder) faces of its tile's survivor list — equal work, no imbalance.
// Face records gathered cooperatively into LDS; inner loop is LDS-broadcast.
__global__ __launch_bounds__(256) void passB(const float* __restrict__ fdata,
                                             const unsigned short* __restrict__ slist,
                                             const int* __restrict__ scount,
                                             unsigned long long* __restrict__ zbest) {
#pragma clang fp contract(off)
    const int bt   = blockIdx.x;
    const int cnt  = scount[bt];
    const int start = blockIdx.y * SEG;
    if (start >= cnt) return;
    const int n = min(SEG, cnt - start);

    __shared__ float4 sface[SEG * 4];   // 2 KB
    __shared__ int    sidx[SEG];
    const int tid  = threadIdx.x;
    const int b    = bt >> 6;
    const int tile = bt & 63;

    if (tid < n) sidx[tid] = (int)slist[(size_t)bt * F + start + tid];
    __syncthreads();
    if (tid < 4 * n) {
        int f = sidx[tid >> 2];
        sface[tid] = ((const float4*)fdata)[((size_t)b * F + f) * 4 + (tid & 3)];
    }
    __syncthreads();

    const int ix0 = (tile & 7) * 16, iy0 = (tile >> 3) * 16;
    const int dx = tid & 15, dy = tid >> 4;
    const int ix = ix0 + dx, iy = iy0 + dy;
    const float px = 1.0f - (2.0f * (float)ix + 1.0f) / (float)IMG;
    const float py = 1.0f - (2.0f * (float)iy + 1.0f) / (float)IMG;

    unsigned long long pmin = ~0ULL;
    #pragma unroll 4
    for (int i = 0; i < n; ++i) {
        float4 q0 = sface[i * 4 + 0];
        float4 q1 = sface[i * 4 + 1];
        float4 q2 = sface[i * 4 + 2];
        float4 q3 = sface[i * 4 + 3];
        const int fj = sidx[i];
        const float den = q3.x;
        // exact reference edge functions
        float w0 = q0.x * (py - q0.w) - q0.y * (px - q0.z);
        float w1 = q1.x * (py - q1.w) - q1.y * (px - q1.z);
        float w2 = q2.x * (py - q2.w) - q2.y * (px - q2.z);
        // s_i >= 0  <=>  w_i==0 || sign(w_i)==sign(den)   (den != 0 staged)
        unsigned ds = __float_as_uint(den) >> 31;
        bool in0 = (w0 == 0.0f) || ((__float_as_uint(w0) >> 31) == ds);
        bool in1 = (w1 == 0.0f) || ((__float_as_uint(w1) >> 31) == ds);
        bool in2 = (w2 == 0.0f) || ((__float_as_uint(w2) >> 31) == ds);
        if (in0 & in1 & in2) {
            // exact reference rounding for z (3 IEEE divides)
            float s0 = w0 / den, s1 = w1 / den, s2 = w2 / den;
            float z  = s0 * q3.y + s1 * q3.z + s2 * q3.w;
            if (z > 0.0f) {
                unsigned long long pk =
                    ((unsigned long long)__float_as_uint(z) << 32) | (unsigned)fj;
                pmin = pmin < pk ? pmin : pk;
            }
        }
    }
    if (pmin != ~0ULL) atomicMin(&zbest[b * NPIX + iy * IMG + ix], pmin);
}

// Unpack winner; recompute bary + dists from fdata (reference-rounded values).
__global__ __launch_bounds__(256) void pass2(const float* __restrict__ fdata,
                                             const unsigned long long* __restrict__ zbest,
                                             float* __restrict__ out) {
#pragma clang fp contract(off)
    const int gp = blockIdx.x * 256 + threadIdx.x;
    const int b  = gp >> 14;
    const int p  = gp & (NPIX - 1);
    const int ix = p & (IMG - 1), iy = p >> 7;

    unsigned long long packed = zbest[gp];
    float o_face = -1.0f, o_z = -1.0f, o_b0 = -1.0f, o_b1 = -1.0f,
          o_b2 = -1.0f, o_d = -1.0f;

    if (packed != ~0ULL) {
        const int   idx = (int)(unsigned)(packed & 0xffffffffu);
        const float z   = __uint_as_float((unsigned)(packed >> 32));
        const float px  = 1.0f - (2.0f * (float)ix + 1.0f) / (float)IMG;
        const float py  = 1.0f - (2.0f * (float)iy + 1.0f) / (float)IMG;

        const float4* fd4 = (const float4*)(fdata + (((size_t)b * F + idx) << 4));
        float4 q0 = fd4[0], q1 = fd4[1], q2 = fd4[2], q3 = fd4[3];
        float den = q3.x;
        float w0 = q0.x * (py - q0.w) - q0.y * (px - q0.z);
        float w1 = q1.x * (py - q1.w) - q1.y * (px - q1.z);
        float w2 = q2.x * (py - q2.w) - q2.y * (px - q2.z);
        float s0 = w0 / den, s1 = w1 / den, s2 = w2 / den;

        // a=(q2.z,q2.w)  b=(q0.z,q0.w)  c=(q1.z,q1.w): reference-rounded coords
        float d2 = fminf(fminf(seg_dist2(px, py, q2.z, q2.w, q0.z, q0.w),
                               seg_dist2(px, py, q0.z, q0.w, q1.z, q1.w)),
                         seg_dist2(px, py, q1.z, q1.w, q2.z, q2.w));
        o_face = (float)idx; o_z = z;
        o_b0 = s0; o_b1 = s1; o_b2 = s2;
        o_d = -d2;
    }

    out[gp]            = o_face;
    out[B * NPIX + gp] = o_z;
    const int bary_base = 2 * B * NPIX;
    out[bary_base + gp * 3 + 0] = o_b0;
    out[bary_base + gp * 3 + 1] = o_b1;
    out[bary_base + gp * 3 + 2] = o_b2;
    out[5 * B * NPIX + gp] = o_d;
}

} // namespace

extern "C" void kernel_launch(void* const* d_in, const int* in_sizes, int n_in,
                              void* d_out, int out_size, void* d_ws, size_t ws_size,
                              hipStream_t stream) {
    const float* verts = (const float*)d_in[0];  // (B,V,3) f32
    const int*   faces = (const int*)d_in[1];    // (F,3) i32
    float* out = (float*)d_out;

    // ws layout: zbest 512KB | fdata 256KB | scount 1KB | slist 512KB  (~1.26MB)
    char* ws = (char*)d_ws;
    unsigned long long* zbest = (unsigned long long*)ws;                 // B*NPIX*8
    float*          fdata  = (float*)(ws + (size_t)B * NPIX * 8);        // B*F*64
    int*            scount = (int*)(ws + (size_t)B * NPIX * 8 + (size_t)B * F * 64);
    unsigned short* slist  = (unsigned short*)(ws + (size_t)B * NPIX * 8 +
                                               (size_t)B * F * 64 + 1024);

    setup_clear<<<B * NPIX / 256, 256, 0, stream>>>(verts, faces, fdata, zbest);
    binA<<<B * 64, 256, 0, stream>>>(fdata, slist, scount);
    passB<<<dim3(B * 64, NSEG), dim3(256), 0, stream>>>(fdata, slist, scount, zbest);
    pass2<<<B * NPIX / 256, 256, 0, stream>>>(fdata, zbest, out);
}